// Round 8
// baseline (11240.316 us; speedup 1.0000x reference)
//
#include <hip/hip_runtime.h>
#include <hip/hip_bf16.h>
#include <cstdio>

// ---------- types / helpers ----------
typedef __attribute__((ext_vector_type(4))) float f32x4;
typedef __attribute__((ext_vector_type(8))) short bf16x8;  // 8 bf16 raw

__device__ __forceinline__ short f2b(float f) {
  unsigned u = __builtin_bit_cast(unsigned, f);
  unsigned r = (u + 0x7FFFu + ((u >> 16) & 1u)) >> 16;  // RNE
  return (short)r;
}
__device__ __forceinline__ float b2f(short s) {
  union { unsigned u; float f; } c;
  c.u = ((unsigned)(unsigned short)s) << 16;
  return c.f;
}
__device__ __forceinline__ float sigm(float x) { return 1.f / (1.f + __expf(-x)); }
__device__ __forceinline__ float tanh_f(float x) {
  float e = __expf(2.f * x);
  return 1.f - 2.f / (e + 1.f);
}
__device__ __forceinline__ f32x4 c4(const short* p) {  // 4 bf16 (LDS) -> f32x4
  f32x4 r; r[0] = b2f(p[0]); r[1] = b2f(p[1]); r[2] = b2f(p[2]); r[3] = b2f(p[3]);
  return r;
}

// Problem dims: B=8 T=64 F=8 N=4096 H=32 G=32 K1=K2=3 R1=64 R2=8

// ---------- fp32 -> bf16 convert ----------
__global__ void conv_k(const float* __restrict__ in, short* __restrict__ out, int n8) {
  int i = blockIdx.x * 256 + threadIdx.x;
  if (i >= n8) return;
  size_t base = (size_t)i * 8;
  f32x4 a = *(const f32x4*)(in + base), b = *(const f32x4*)(in + base + 4);
  bf16x8 v;
#pragma unroll
  for (int j = 0; j < 4; ++j) { v[j] = f2b(a[j]); v[4 + j] = f2b(b[j]); }
  *(bf16x8*)(out + base) = v;
}

// ---------- transpose+convert (fp32 4096x4096 -> bf16) ----------
__global__ void transpose_k(const float* __restrict__ in, short* __restrict__ out) {
  __shared__ float tile[32][33];
  int bx = blockIdx.x * 32, by = blockIdx.y * 32;
  int tx = threadIdx.x, ty = threadIdx.y;
  for (int i = ty; i < 32; i += 8)
    tile[i][tx] = in[(size_t)(by + i) * 4096 + bx + tx];
  __syncthreads();
  for (int i = ty; i < 32; i += 8)
    out[(size_t)(bx + i) * 4096 + by + tx] = f2b(tile[tx][i]);
}

// ---------- preamble GEMM: C[M][N] = A[M][K] * Bt[N][K]^T ----------
template <int AF32>
__global__ __launch_bounds__(256) void gemm_pre(const void* __restrict__ Av,
                                                const short* __restrict__ Bt,
                                                short* __restrict__ C,
                                                int K, int ldc) {
  __shared__ __align__(16) short As[128][72];
  __shared__ __align__(16) short Bs[128][72];
  const int tid = threadIdx.x;
  const int lane = tid & 63, wave = tid >> 6;
  const int wm = wave >> 1, wn = wave & 1;
  const size_t m0 = (size_t)blockIdx.y * 128, n0 = (size_t)blockIdx.x * 128;
  const int r16 = lane & 15, g4 = lane >> 4;

  f32x4 acc[4][4];
#pragma unroll
  for (int mi = 0; mi < 4; ++mi)
#pragma unroll
    for (int ni = 0; ni < 4; ++ni) acc[mi][ni] = (f32x4)0.f;

  for (int kt = 0; kt < K; kt += 64) {
#pragma unroll
    for (int r = 0; r < 4; ++r) {
      int idx = r * 256 + tid;
      int row = idx >> 3;
      int kin = (idx & 7) * 8;
      if (AF32) {
        const float* A = (const float*)Av;
        const float* p = &A[(m0 + row) * (size_t)K + kt + kin];
        f32x4 a = *(const f32x4*)p, b = *(const f32x4*)(p + 4);
        bf16x8 v;
#pragma unroll
        for (int j = 0; j < 4; ++j) { v[j] = f2b(a[j]); v[4 + j] = f2b(b[j]); }
        *(bf16x8*)&As[row][kin] = v;
      } else {
        const short* A = (const short*)Av;
        *(bf16x8*)&As[row][kin] = *(const bf16x8*)&A[(m0 + row) * (size_t)K + kt + kin];
      }
      *(bf16x8*)&Bs[row][kin] = *(const bf16x8*)&Bt[(n0 + row) * (size_t)K + kt + kin];
    }
    __syncthreads();
#pragma unroll
    for (int ks = 0; ks < 2; ++ks) {
      bf16x8 af[4], bfr[4];
#pragma unroll
      for (int i = 0; i < 4; ++i) {
        af[i]  = *(const bf16x8*)&As[wm * 64 + i * 16 + r16][ks * 32 + g4 * 8];
        bfr[i] = *(const bf16x8*)&Bs[wn * 64 + i * 16 + r16][ks * 32 + g4 * 8];
      }
#pragma unroll
      for (int mi = 0; mi < 4; ++mi)
#pragma unroll
        for (int ni = 0; ni < 4; ++ni)
          acc[mi][ni] = __builtin_amdgcn_mfma_f32_16x16x32_bf16(af[mi], bfr[ni], acc[mi][ni], 0, 0, 0);
    }
    __syncthreads();
  }
#pragma unroll
  for (int mi = 0; mi < 4; ++mi) {
#pragma unroll
    for (int ni = 0; ni < 4; ++ni) {
      size_t row0 = m0 + wm * 64 + mi * 16 + g4 * 4;
      size_t col  = n0 + wn * 64 + ni * 16 + r16;
#pragma unroll
      for (int r = 0; r < 4; ++r)
        C[(row0 + r) * (size_t)ldc + col] = f2b(acc[mi][ni][r]);
    }
  }
}

// ---------- hand-rolled grid barrier (generation counting, 256 blocks) ----------
__device__ __forceinline__ void gridbar(unsigned* cnt, unsigned* gen) {
  __syncthreads();
  if (threadIdx.x == 0) {
    unsigned g = __hip_atomic_load(gen, __ATOMIC_RELAXED, __HIP_MEMORY_SCOPE_AGENT);
    __threadfence();
    if (__hip_atomic_fetch_add(cnt, 1u, __ATOMIC_ACQ_REL, __HIP_MEMORY_SCOPE_AGENT) == 255u) {
      __hip_atomic_store(cnt, 0u, __ATOMIC_RELAXED, __HIP_MEMORY_SCOPE_AGENT);
      __hip_atomic_fetch_add(gen, 1u, __ATOMIC_RELEASE, __HIP_MEMORY_SCOPE_AGENT);
    } else {
      while (__hip_atomic_load(gen, __ATOMIC_ACQUIRE, __HIP_MEMORY_SCOPE_AGENT) == g)
        __builtin_amdgcn_s_sleep(8);
    }
    __threadfence();
  }
  __syncthreads();
}

// ---------- persistent recurrence kernel ----------
// 256 blocks x 512 threads, 1 block/CU (LDS 62.7KB, VGPR<=256 via launch_bounds).
// Block (mhalf, ntile): z-rows m0..m0+127 (4 batches), node cols n0..n0+31.
// Per step: GEMM taps (stay in LDS) -> out(tau=t-1) -> gate (za/zb in regs)
//           -> gridbar (gacc pooled) -> in-register update -> gridbar.
__global__ __launch_bounds__(512, 1) void rnn_persist(
    short* __restrict__ zbuf, const short* __restrict__ Scat,
    const float* __restrict__ x, const short* __restrict__ xsh,
    const float* __restrict__ Ca, const float* __restrict__ Cb, const float* __restrict__ bc,
    const float* __restrict__ Da, const float* __restrict__ Db, const float* __restrict__ bd,
    const float* __restrict__ Af, const float* __restrict__ Bw, const float* __restrict__ bz,
    const float* __restrict__ Wout, const float* __restrict__ bout,
    const float* __restrict__ W1, const float* __restrict__ b1,
    const float* __restrict__ W2, const float* __restrict__ b2,
    float* __restrict__ out, float* __restrict__ gacc, unsigned* __restrict__ bar) {
  __shared__ __align__(16) char smem[62688];
  short* As  = (short*)smem;               // [128][72] GEMM A tile / C tile (bf16)
  short* Bs  = (short*)(smem + 18432);     // [64][72] GEMM B tile / z-tile [128][32]
  short* FuH = (short*)(smem + 27648);     // [120][32] bf16
  short* FdH = (short*)(smem + 35328);     // [120][32]
  short* FbH = (short*)(smem + 43008);     // [96][32]
  short* FaH = (short*)(smem + 49152);     // [24][32]
  short* WcH = (short*)(smem + 50688);     // [96][32]
  short* W1H = (short*)(smem + 56832);     // [64][32]
  short* W2H = (short*)(smem + 60928);     // [64][8]
  float* bcs   = (float*)(smem + 61952);   // [32]
  float* bds   = (float*)(smem + 62080);   // [32]
  float* boutL = (float*)(smem + 62208);   // [32]
  float* b1L   = (float*)(smem + 62336);   // [64]
  float* b2L   = (float*)(smem + 62592);   // [8]
  float* red   = (float*)(smem + 62624);   // [16]

  const int tid = threadIdx.x;
  const int lane = tid & 63, w = tid >> 6;
  const int wm = w >> 1, wn = w & 1;
  const int r16 = lane & 15, g4 = lane >> 4;
  const int mhalf = blockIdx.x >> 7, ntile = blockIdx.x & 127;
  const int m0 = mhalf << 7, n0 = ntile << 5;

  // ---- load all filters once (bf16 in LDS) ----
  for (int i = tid; i < 3840; i += 512) {
    int j = i >> 5, h = i & 31; float fu, fd;
    if (j < 96) { int k = j >> 5, hh = j & 31;
      fu = Cb[(h * 3 + k) * 32 + hh]; fd = Db[(h * 3 + k) * 32 + hh]; }
    else { int jj = j - 96, k = jj >> 3, f = jj & 7;
      fu = Ca[(h * 3 + k) * 8 + f];  fd = Da[(h * 3 + k) * 8 + f]; }
    FuH[i] = f2b(fu); FdH[i] = f2b(fd);
  }
  for (int i = tid; i < 3072; i += 512) { int j = i >> 5, h = i & 31, k = j >> 5, hh = j & 31;
    FbH[i] = f2b(Bw[(h * 3 + k) * 32 + hh]); }
  for (int i = tid; i < 768;  i += 512) { int j = i >> 5, h = i & 31, k = j >> 3, f = j & 7;
    FaH[i] = f2b(Af[(h * 3 + k) * 8 + f]); }
  for (int i = tid; i < 3072; i += 512) { int j = i >> 5, g = i & 31, k = j >> 5, hh = j & 31;
    WcH[i] = f2b(Wout[(g * 3 + k) * 32 + hh]); }
  for (int i = tid; i < 2048; i += 512) { int r1 = i >> 5, g = i & 31; W1H[i] = f2b(W1[r1 * 32 + g]); }
  if (tid < 512) { int r1 = tid >> 3, r = tid & 7; W2H[tid] = f2b(W2[r * 64 + r1]); }
  if (tid < 32) { bcs[tid] = bc[tid]; bds[tid] = bd[tid]; boutL[tid] = bout[tid]; }
  if (tid < 64) b1L[tid] = b1[tid];
  if (tid < 8)  b2L[tid] = b2[tid];
  __syncthreads();

  for (int t = 0; t <= 64; ++t) {
    const short* z = zbuf + (size_t)(t & 1) * 1048576;
    // ---- GEMM: C[128][64] = z[m0..+128][:] x [S;S2] rows of this n-tile ----
    f32x4 acc[2][2];
    acc[0][0] = acc[0][1] = acc[1][0] = acc[1][1] = (f32x4)0.f;
    for (int kt = 0; kt < 4096; kt += 64) {
#pragma unroll
      for (int r = 0; r < 2; ++r) {
        int idx = r * 512 + tid, row = idx >> 3, kin = (idx & 7) * 8;
        *(bf16x8*)&As[row * 72 + kin] = *(const bf16x8*)&z[(size_t)(m0 + row) * 4096 + kt + kin];
      }
      { int row = tid >> 3, kin = (tid & 7) * 8;
        int grow = (row < 32) ? (n0 + row) : (4064 + n0 + row);   // tap1 | tap2 (S^2)
        *(bf16x8*)&Bs[row * 72 + kin] = *(const bf16x8*)&Scat[(size_t)grow * 4096 + kt + kin]; }
      __syncthreads();
#pragma unroll
      for (int ks = 0; ks < 2; ++ks) {
        bf16x8 af[2], bb[2];
#pragma unroll
        for (int i = 0; i < 2; ++i) {
          af[i] = *(const bf16x8*)&As[(wm * 32 + i * 16 + r16) * 72 + ks * 32 + g4 * 8];
          bb[i] = *(const bf16x8*)&Bs[(wn * 32 + i * 16 + r16) * 72 + ks * 32 + g4 * 8];
        }
#pragma unroll
        for (int mi = 0; mi < 2; ++mi)
#pragma unroll
          for (int ni = 0; ni < 2; ++ni)
            acc[mi][ni] = __builtin_amdgcn_mfma_f32_16x16x32_bf16(af[mi], bb[ni], acc[mi][ni], 0, 0, 0);
      }
      __syncthreads();
    }
    // ---- C tile -> LDS (overlay As); z-tile (k=0 tap) -> LDS (overlay Bs) ----
    short* Cs = As;   // [128][72], cols 0..63 = [tap1(32) | tap2(32)]
    short* zs = Bs;   // [128][32]
#pragma unroll
    for (int mi = 0; mi < 2; ++mi)
#pragma unroll
      for (int ni = 0; ni < 2; ++ni) {
        int row0 = wm * 32 + mi * 16 + g4 * 4, col = wn * 32 + ni * 16 + r16;
#pragma unroll
        for (int rr = 0; rr < 4; ++rr)
          Cs[(row0 + rr) * 72 + col] = f2b(acc[mi][ni][rr]);
      }
    { int row = tid >> 2, c0 = (tid & 3) * 8;
      *(bf16x8*)&zs[row * 32 + c0] = *(const bf16x8*)&z[(size_t)(m0 + row) * 4096 + n0 + c0]; }
    __syncthreads();

    // ---- OUT phase (tau = t-1), threads 0..127 ----
    if (t >= 1 && tid < 128) {
      int b_loc = tid >> 5, nn = tid & 31;
      int b_glob = (mhalf << 2) + b_loc;
      f32x4 oa[8];
#pragma unroll
      for (int q = 0; q < 8; ++q) oa[q] = (f32x4)0.f;
      for (int j = 0; j < 96; ++j) {
        int k = j >> 5, hh = j & 31;
        float v = (k == 0) ? b2f(zs[(b_loc * 32 + hh) * 32 + nn])
                           : b2f(Cs[(b_loc * 32 + hh) * 72 + (k - 1) * 32 + nn]);
#pragma unroll
        for (int q = 0; q < 8; ++q) oa[q] += c4(WcH + j * 32 + q * 4) * v;
      }
      f32x4 y[8];
#pragma unroll
      for (int q = 0; q < 8; ++q)
#pragma unroll
        for (int c = 0; c < 4; ++c) y[q][c] = tanh_f(oa[q][c] + boutL[q * 4 + c]);
      f32x4 o0 = { b2L[0], b2L[1], b2L[2], b2L[3] };
      f32x4 o1 = { b2L[4], b2L[5], b2L[6], b2L[7] };
      for (int r1 = 0; r1 < 64; ++r1) {
        f32x4 p = y[0] * c4(W1H + r1 * 32);
#pragma unroll
        for (int q = 1; q < 8; ++q) p += y[q] * c4(W1H + r1 * 32 + q * 4);
        float hv = b1L[r1] + p[0] + p[1] + p[2] + p[3];
        hv = fmaxf(hv, 0.f);
        o0 += c4(W2H + r1 * 8) * hv;
        o1 += c4(W2H + r1 * 8 + 4) * hv;
      }
      size_t obase = ((size_t)(b_glob * 64 + (t - 1)) * 8) * 4096 + n0 + nn;
#pragma unroll
      for (int rr = 0; rr < 4; ++rr) {
        out[obase + (size_t)rr * 4096]       = o0[rr];
        out[obase + (size_t)(4 + rr) * 4096] = o1[rr];
      }
    }

    // ---- GATE phase (za/zb kept in registers across the barrier) ----
    f32x4 guA = (f32x4)0.f, guB = (f32x4)0.f, gdA = (f32x4)0.f, gdB = (f32x4)0.f;
    f32x4 zaA = (f32x4)0.f, zaB = (f32x4)0.f, zbA = (f32x4)0.f, zbB = (f32x4)0.f;
    int b_glob = 0, b_loc = 0, h0 = 0, nn = 0;
    if (t < 64) {
      nn = tid & 31; int q = tid >> 5; b_loc = q >> 2; h0 = (q & 3) * 8;
      b_glob = (mhalf << 2) + b_loc;
      guA = { bcs[h0], bcs[h0 + 1], bcs[h0 + 2], bcs[h0 + 3] };
      guB = { bcs[h0 + 4], bcs[h0 + 5], bcs[h0 + 6], bcs[h0 + 7] };
      gdA = { bds[h0], bds[h0 + 1], bds[h0 + 2], bds[h0 + 3] };
      gdB = { bds[h0 + 4], bds[h0 + 5], bds[h0 + 6], bds[h0 + 7] };
      for (int j = 0; j < 96; ++j) {                 // z taps
        int k = j >> 5, hh = j & 31;
        float v = (k == 0) ? b2f(zs[(b_loc * 32 + hh) * 32 + nn])
                           : b2f(Cs[(b_loc * 32 + hh) * 72 + (k - 1) * 32 + nn]);
        guA += c4(FuH + j * 32 + h0) * v;  guB += c4(FuH + j * 32 + h0 + 4) * v;
        gdA += c4(FdH + j * 32 + h0) * v;  gdB += c4(FdH + j * 32 + h0 + 4) * v;
        zbA += c4(FbH + j * 32 + h0) * v;  zbB += c4(FbH + j * 32 + h0 + 4) * v;
      }
      size_t xr = ((size_t)b_glob * 64 + t) * 8;
      for (int j = 0; j < 24; ++j) {                 // x taps
        int k = j >> 3, f = j & 7;
        float v = (k == 0) ? x[(xr + f) * 4096 + n0 + nn]
                           : b2f(xsh[(xr + f) * 8192 + (size_t)(k - 1) * 4096 + n0 + nn]);
        guA += c4(FuH + (96 + j) * 32 + h0) * v;  guB += c4(FuH + (96 + j) * 32 + h0 + 4) * v;
        gdA += c4(FdH + (96 + j) * 32 + h0) * v;  gdB += c4(FdH + (96 + j) * 32 + h0 + 4) * v;
        zaA += c4(FaH + j * 32 + h0) * v;         zaB += c4(FaH + j * 32 + h0 + 4) * v;
      }
      float su = 0.f, sd = 0.f;
#pragma unroll
      for (int i = 0; i < 4; ++i) {
        su += sigm(guA[i]) + sigm(guB[i]);
        sd += sigm(gdA[i]) + sigm(gdB[i]);
      }
#pragma unroll
      for (int off = 32; off; off >>= 1) { su += __shfl_down(su, off); sd += __shfl_down(sd, off); }
      if (lane == 0) { red[w * 2] = su; red[w * 2 + 1] = sd; }
      __syncthreads();
      if (tid < 4) {
        int par = t & 1, bg = (mhalf << 2) + tid;
        atomicAdd(&gacc[par * 16 + bg],     red[tid * 4] + red[tid * 4 + 2]);
        atomicAdd(&gacc[par * 16 + 8 + bg], red[tid * 4 + 1] + red[tid * 4 + 3]);
      }
    }
    gridbar(bar, bar + 1);     // gacc complete
    if (t < 64) {
      int par = t & 1;
      float u  = gacc[par * 16 + b_glob]     * (1.f / 131072.f);
      float fg = gacc[par * 16 + 8 + b_glob] * (1.f / 131072.f);
      short* znxt = zbuf + (size_t)((t + 1) & 1) * 1048576;
#pragma unroll
      for (int i = 0; i < 4; ++i) {
        znxt[(size_t)(m0 + b_loc * 32 + h0 + i) * 4096 + n0 + nn]
            = f2b(tanh_f(u * zaA[i] + fg * zbA[i] + bz[h0 + i]));
        znxt[(size_t)(m0 + b_loc * 32 + h0 + 4 + i) * 4096 + n0 + nn]
            = f2b(tanh_f(u * zaB[i] + fg * zbB[i] + bz[h0 + 4 + i]));
      }
      if (blockIdx.x == 0 && tid < 16) gacc[((par ^ 1) * 16) + tid] = 0.f;
    }
    gridbar(bar, bar + 1);     // z_{t+1} complete
  }
}

// ---------- host ----------
extern "C" void kernel_launch(void* const* d_in, const int* in_sizes, int n_in,
                              void* d_out, int out_size, void* d_ws, size_t ws_size,
                              hipStream_t stream) {
  const float* x    = (const float*)d_in[0];
  const float* z0   = (const float*)d_in[1];
  const float* S    = (const float*)d_in[2];
  const float* Af   = (const float*)d_in[3];
  const float* Bw   = (const float*)d_in[4];
  const float* bz   = (const float*)d_in[5];
  const float* Ca   = (const float*)d_in[6];
  const float* Cb   = (const float*)d_in[7];
  const float* bc   = (const float*)d_in[8];
  const float* Da   = (const float*)d_in[9];
  const float* Db   = (const float*)d_in[10];
  const float* bd   = (const float*)d_in[11];
  const float* Wout = (const float*)d_in[12];
  const float* bo   = (const float*)d_in[13];
  const float* W1   = (const float*)d_in[14];
  const float* b1   = (const float*)d_in[15];
  const float* W2   = (const float*)d_in[16];
  const float* b2   = (const float*)d_in[17];
  float* out = (float*)d_out;

  // workspace layout (~138.6 MiB)
  char* w = (char*)d_ws;
  short* Scat = (short*)w; w += (size_t)8192 * 4096 * 2;   // bf16 [S ; S^2]          67.1 MB
  short* xsh  = (short*)w; w += (size_t)4096 * 8192 * 2;   // bf16 x shifts (tmp S^T) 67.1 MB
  short* zbuf = (short*)w; w += (size_t)2 * 1048576 * 2;   // bf16 z ping-pong         4.2 MB
  float* gacc = (float*)w; w += 128;                       // 2 parities x 16 floats
  unsigned* bar = (unsigned*)w; w += 128;                  // barrier cnt+gen
  size_t need = (size_t)(w - (char*)d_ws);
  if (ws_size < need) {
    fprintf(stderr, "kernel_launch: WS TOO SMALL need=%zu have=%zu -- NOT LAUNCHING\n",
            need, ws_size);
    return;
  }

  short* STt = xsh;  // temp: bf16 S^T (consumed by S^2 GEMM before xsh is written)

  conv_k<<<512, 256, 0, stream>>>(z0, zbuf, 131072);            // bf16 z_0 -> slot 0
  conv_k<<<8192, 256, 0, stream>>>(S, Scat, 2097152);           // bf16 S
  transpose_k<<<dim3(128, 128), dim3(32, 8), 0, stream>>>(S, STt);
  gemm_pre<0><<<dim3(32, 32), 256, 0, stream>>>(Scat, STt, Scat + (size_t)4096 * 4096, 4096, 4096);
  gemm_pre<1><<<dim3(64, 32), 256, 0, stream>>>(x, Scat, xsh, 4096, 8192);
  hipMemsetAsync(gacc, 0, 128, stream);
  hipMemsetAsync(bar, 0, 8, stream);

  rnn_persist<<<256, 512, 0, stream>>>(zbuf, Scat, x, xsh,
                                       Ca, Cb, bc, Da, Db, bd, Af, Bw, bz,
                                       Wout, bo, W1, b1, W2, b2,
                                       out, gacc, bar);
}

// Round 9
// 7948.121 us; speedup vs baseline: 1.4142x; 1.4142x over previous
//
#include <hip/hip_runtime.h>
#include <hip/hip_bf16.h>
#include <cstdio>

// ---------- types / helpers ----------
typedef __attribute__((ext_vector_type(4))) float f32x4;
typedef __attribute__((ext_vector_type(8))) short bf16x8;  // 8 bf16 raw

__device__ __forceinline__ short f2b(float f) {
  unsigned u = __builtin_bit_cast(unsigned, f);
  unsigned r = (u + 0x7FFFu + ((u >> 16) & 1u)) >> 16;  // RNE
  return (short)r;
}
__device__ __forceinline__ float b2f(short s) {
  union { unsigned u; float f; } c;
  c.u = ((unsigned)(unsigned short)s) << 16;
  return c.f;
}
__device__ __forceinline__ float sigm(float x) { return 1.f / (1.f + __expf(-x)); }
__device__ __forceinline__ float tanh_f(float x) {
  float e = __expf(2.f * x);
  return 1.f - 2.f / (e + 1.f);
}

#define GLOAD16(gp, lp) \
  __builtin_amdgcn_global_load_lds((__attribute__((address_space(1))) const void*)(gp), \
                                   (__attribute__((address_space(3))) void*)(lp), 16, 0, 0)

// Problem dims: B=8 T=64 F=8 N=4096 H=32 G=32 K1=K2=3 R1=64 R2=8

// ---------- fp32 -> bf16 convert ----------
__global__ void conv_k(const float* __restrict__ in, short* __restrict__ out, int n8) {
  int i = blockIdx.x * 256 + threadIdx.x;
  if (i >= n8) return;
  size_t base = (size_t)i * 8;
  f32x4 a = *(const f32x4*)(in + base), b = *(const f32x4*)(in + base + 4);
  bf16x8 v;
#pragma unroll
  for (int j = 0; j < 4; ++j) { v[j] = f2b(a[j]); v[4 + j] = f2b(b[j]); }
  *(bf16x8*)(out + base) = v;
}

// ---------- transpose+convert (fp32 4096x4096 -> bf16) ----------
__global__ void transpose_k(const float* __restrict__ in, short* __restrict__ out) {
  __shared__ float tile[32][33];
  int bx = blockIdx.x * 32, by = blockIdx.y * 32;
  int tx = threadIdx.x, ty = threadIdx.y;
  for (int i = ty; i < 32; i += 8)
    tile[i][tx] = in[(size_t)(by + i) * 4096 + bx + tx];
  __syncthreads();
  for (int i = ty; i < 32; i += 8)
    out[(size_t)(bx + i) * 4096 + by + tx] = f2b(tile[tx][i]);
}

// ---------- preamble GEMM: C[M][N] = A[M][K] * Bt[N][K]^T ----------
template <int AF32>
__global__ __launch_bounds__(256) void gemm_pre(const void* __restrict__ Av,
                                                const short* __restrict__ Bt,
                                                short* __restrict__ C,
                                                int K, int ldc) {
  __shared__ __align__(16) short As[128][72];
  __shared__ __align__(16) short Bs[128][72];
  const int tid = threadIdx.x;
  const int lane = tid & 63, wave = tid >> 6;
  const int wm = wave >> 1, wn = wave & 1;
  const size_t m0 = (size_t)blockIdx.y * 128, n0 = (size_t)blockIdx.x * 128;
  const int r16 = lane & 15, g4 = lane >> 4;

  f32x4 acc[4][4];
#pragma unroll
  for (int mi = 0; mi < 4; ++mi)
#pragma unroll
    for (int ni = 0; ni < 4; ++ni) acc[mi][ni] = (f32x4)0.f;

  for (int kt = 0; kt < K; kt += 64) {
#pragma unroll
    for (int r = 0; r < 4; ++r) {
      int idx = r * 256 + tid;
      int row = idx >> 3;
      int kin = (idx & 7) * 8;
      if (AF32) {
        const float* A = (const float*)Av;
        const float* p = &A[(m0 + row) * (size_t)K + kt + kin];
        f32x4 a = *(const f32x4*)p, b = *(const f32x4*)(p + 4);
        bf16x8 v;
#pragma unroll
        for (int j = 0; j < 4; ++j) { v[j] = f2b(a[j]); v[4 + j] = f2b(b[j]); }
        *(bf16x8*)&As[row][kin] = v;
      } else {
        const short* A = (const short*)Av;
        *(bf16x8*)&As[row][kin] = *(const bf16x8*)&A[(m0 + row) * (size_t)K + kt + kin];
      }
      *(bf16x8*)&Bs[row][kin] = *(const bf16x8*)&Bt[(n0 + row) * (size_t)K + kt + kin];
    }
    __syncthreads();
#pragma unroll
    for (int ks = 0; ks < 2; ++ks) {
      bf16x8 af[4], bfr[4];
#pragma unroll
      for (int i = 0; i < 4; ++i) {
        af[i]  = *(const bf16x8*)&As[wm * 64 + i * 16 + r16][ks * 32 + g4 * 8];
        bfr[i] = *(const bf16x8*)&Bs[wn * 64 + i * 16 + r16][ks * 32 + g4 * 8];
      }
#pragma unroll
      for (int mi = 0; mi < 4; ++mi)
#pragma unroll
        for (int ni = 0; ni < 4; ++ni)
          acc[mi][ni] = __builtin_amdgcn_mfma_f32_16x16x32_bf16(af[mi], bfr[ni], acc[mi][ni], 0, 0, 0);
    }
    __syncthreads();
  }
#pragma unroll
  for (int mi = 0; mi < 4; ++mi) {
#pragma unroll
    for (int ni = 0; ni < 4; ++ni) {
      size_t row0 = m0 + wm * 64 + mi * 16 + g4 * 4;
      size_t col  = n0 + wn * 64 + ni * 16 + r16;
#pragma unroll
      for (int r = 0; r < 4; ++r)
        C[(row0 + r) * (size_t)ldc + col] = f2b(acc[mi][ni][r]);
    }
  }
}

// ---------- per-step z-shift GEMM, pipelined (global_load_lds + dbuf + swizzle) ----------
// zsh[256][8192] bf16: cols 0..4095 = S*z taps, 4096..8191 = S^2*z taps.
// grid (128 ntiles of 64 cols, 2 mhalves of 128 rows), block 256 = 4 waves (2m x 2n).
// LDS linear [rows][64]; 16B-slot s of row r holds logical slot s^(r&7)
// (pre-swizzled global source, swizzled ds_read -> conflict-free b128 reads).
__global__ __launch_bounds__(256) void gemm_zsh2(const short* __restrict__ z,
                                                 const short* __restrict__ Scat,
                                                 short* __restrict__ zsh) {
  __shared__ __align__(16) short Ab[2][128 * 64];
  __shared__ __align__(16) short Bb[2][64 * 64];
  const int tid = threadIdx.x, lane = tid & 63, w = tid >> 6;
  const int wm = w >> 1, wn = w & 1;
  const int r16 = lane & 15, g4 = lane >> 4;
  const int m0 = blockIdx.y * 128;
  const int g0 = blockIdx.x * 64;          // Scat row base == zsh col base
  const int lrow8 = lane >> 3;             // 0..7
  const int lslot = (lane & 7) ^ lrow8;    // logical 16B slot for this lane
  const int swz = r16 & 7;                 // read-side slot xor

  f32x4 acc[4][2];
#pragma unroll
  for (int mi = 0; mi < 4; ++mi)
#pragma unroll
    for (int ni = 0; ni < 2; ++ni) acc[mi][ni] = (f32x4)0.f;

  // stage K-tile kt into buffer bs (async, per-wave-uniform LDS dest)
  auto stage = [&](int bs, int kt) {
#pragma unroll
    for (int i = 0; i < 4; ++i) {          // A: 128x64 = 16KB, 4 calls/wave
      int chunk = w * 4 + i;
      int row = chunk * 8 + lrow8;
      GLOAD16(&z[(size_t)(m0 + row) * 4096 + kt + lslot * 8], &Ab[bs][chunk * 512]);
    }
#pragma unroll
    for (int i = 0; i < 2; ++i) {          // B: 64x64 = 8KB, 2 calls/wave
      int chunk = w * 2 + i;
      int row = chunk * 8 + lrow8;
      GLOAD16(&Scat[(size_t)(g0 + row) * 4096 + kt + lslot * 8], &Bb[bs][chunk * 512]);
    }
  };

  stage(0, 0);
  __syncthreads();
  int cur = 0;
  for (int kt = 0; kt < 4096; kt += 64) {
    if (kt + 64 < 4096) stage(cur ^ 1, kt + 64);   // async prefetch next tile
#pragma unroll
    for (int ks = 0; ks < 2; ++ks) {
      const int so = ((ks * 4 + g4) ^ swz) * 8;    // swizzled 16B slot offset (shorts)
      bf16x8 af[4], bb[2];
#pragma unroll
      for (int i = 0; i < 4; ++i)
        af[i] = *(const bf16x8*)&Ab[cur][(wm * 64 + i * 16 + r16) * 64 + so];
#pragma unroll
      for (int i = 0; i < 2; ++i)
        bb[i] = *(const bf16x8*)&Bb[cur][(wn * 32 + i * 16 + r16) * 64 + so];
#pragma unroll
      for (int mi = 0; mi < 4; ++mi)
#pragma unroll
        for (int ni = 0; ni < 2; ++ni)
          acc[mi][ni] = __builtin_amdgcn_mfma_f32_16x16x32_bf16(af[mi], bb[ni], acc[mi][ni], 0, 0, 0);
    }
    __syncthreads();                                // drains stage (vmcnt) + orders LDS
    cur ^= 1;
  }
#pragma unroll
  for (int mi = 0; mi < 4; ++mi)
#pragma unroll
    for (int ni = 0; ni < 2; ++ni) {
      int row0 = m0 + wm * 64 + mi * 16 + g4 * 4;
      int col  = g0 + wn * 32 + ni * 16 + r16;
#pragma unroll
      for (int rr = 0; rr < 4; ++rr)
        zsh[(size_t)(row0 + rr) * 8192 + col] = f2b(acc[mi][ni][rr]);
    }
}

// ---------- fused gate (blocks 0..511) + output stage (blocks 512..639) ----------
__global__ __launch_bounds__(256) void gateout_kernel(
    const float* __restrict__ x, const short* __restrict__ xsh,
    const short* __restrict__ zt, const short* __restrict__ zsh,
    const float* __restrict__ Ca, const float* __restrict__ Cb, const float* __restrict__ bc,
    const float* __restrict__ Da, const float* __restrict__ Db, const float* __restrict__ bd,
    const float* __restrict__ Af, const float* __restrict__ Bw,
    const float* __restrict__ Wout, const float* __restrict__ bout,
    const float* __restrict__ W1, const float* __restrict__ b1,
    const float* __restrict__ W2, const float* __restrict__ b2,
    float* __restrict__ zab, float* __restrict__ gacc,
    float* __restrict__ out, int t) {
  __shared__ __align__(16) float sm[11840];
  const int tid = threadIdx.x;
  const int bid = blockIdx.x;

  if (bid < 512) {
    if (t >= 64) return;
    float* Fu  = sm;            // [120][32]
    float* Fd  = sm + 3840;     // [120][32]
    float* Fb  = sm + 7680;     // [96][32]
    float* Fa  = sm + 10752;    // [24][32]
    float* bcs = sm + 11520;    // [32]
    float* bds = sm + 11552;    // [32]
    float* red = sm + 11584;    // [8]
    for (int i = tid; i < 120 * 32; i += 256) {
      int j = i >> 5, h = i & 31;
      float fu, fd;
      if (j < 96) { int k = j >> 5, hh = j & 31;
        fu = Cb[(h * 3 + k) * 32 + hh]; fd = Db[(h * 3 + k) * 32 + hh]; }
      else { int jj = j - 96, k = jj >> 3, f = jj & 7;
        fu = Ca[(h * 3 + k) * 8 + f];  fd = Da[(h * 3 + k) * 8 + f]; }
      Fu[j * 32 + h] = fu; Fd[j * 32 + h] = fd;
    }
    for (int i = tid; i < 96 * 32; i += 256) { int j = i >> 5, h = i & 31; int k = j >> 5, hh = j & 31;
      Fb[j * 32 + h] = Bw[(h * 3 + k) * 32 + hh]; }
    for (int i = tid; i < 24 * 32; i += 256) { int j = i >> 5, h = i & 31; int k = j >> 3, f = j & 7;
      Fa[j * 32 + h] = Af[(h * 3 + k) * 8 + f]; }
    if (tid < 32) { bcs[tid] = bc[tid]; bds[tid] = bd[tid]; }
    __syncthreads();

    const int b = bid >> 6, chunk = bid & 63;
    const int nn = tid & 63, hg = tid >> 6, h0 = hg * 8;
    const int n = chunk * 64 + nn;
    const size_t zrow = (size_t)b * 32;

    f32x4 guA = *(const f32x4*)&bcs[h0], guB = *(const f32x4*)&bcs[h0 + 4];
    f32x4 gdA = *(const f32x4*)&bds[h0], gdB = *(const f32x4*)&bds[h0 + 4];
    f32x4 zaA = (f32x4)0.f, zaB = (f32x4)0.f, zbA = (f32x4)0.f, zbB = (f32x4)0.f;

    for (int j = 0; j < 96; ++j) {                 // z taps: j = k*32 + h'
      int k = j >> 5, hh = j & 31;
      float v = (k == 0) ? b2f(zt[(zrow + hh) * 4096 + n])
                         : b2f(zsh[(zrow + hh) * 8192 + (size_t)(k - 1) * 4096 + n]);
      f32x4 u0 = *(const f32x4*)&Fu[j * 32 + h0], u1 = *(const f32x4*)&Fu[j * 32 + h0 + 4];
      f32x4 d0 = *(const f32x4*)&Fd[j * 32 + h0], d1 = *(const f32x4*)&Fd[j * 32 + h0 + 4];
      f32x4 p0 = *(const f32x4*)&Fb[j * 32 + h0], p1 = *(const f32x4*)&Fb[j * 32 + h0 + 4];
      guA += u0 * v; guB += u1 * v; gdA += d0 * v; gdB += d1 * v; zbA += p0 * v; zbB += p1 * v;
    }
    const size_t xrow = ((size_t)b * 64 + t) * 8;
    for (int j = 0; j < 24; ++j) {                 // x taps: j = k*8 + f
      int k = j >> 3, f = j & 7;
      float v = (k == 0) ? x[(xrow + f) * 4096 + n]
                         : b2f(xsh[(xrow + f) * 8192 + (size_t)(k - 1) * 4096 + n]);
      f32x4 u0 = *(const f32x4*)&Fu[(96 + j) * 32 + h0], u1 = *(const f32x4*)&Fu[(96 + j) * 32 + h0 + 4];
      f32x4 d0 = *(const f32x4*)&Fd[(96 + j) * 32 + h0], d1 = *(const f32x4*)&Fd[(96 + j) * 32 + h0 + 4];
      f32x4 a0 = *(const f32x4*)&Fa[j * 32 + h0],        a1 = *(const f32x4*)&Fa[j * 32 + h0 + 4];
      guA += u0 * v; guB += u1 * v; gdA += d0 * v; gdB += d1 * v; zaA += a0 * v; zaB += a1 * v;
    }

    float su = 0.f, sd = 0.f;
#pragma unroll
    for (int i = 0; i < 4; ++i) {
      su += sigm(guA[i]) + sigm(guB[i]);
      sd += sigm(gdA[i]) + sigm(gdB[i]);
      zab[(zrow + h0 + i) * 4096 + n]               = zaA[i];
      zab[(zrow + h0 + 4 + i) * 4096 + n]           = zaB[i];
      zab[1048576 + (zrow + h0 + i) * 4096 + n]     = zbA[i];
      zab[1048576 + (zrow + h0 + 4 + i) * 4096 + n] = zbB[i];
    }
    for (int off = 32; off; off >>= 1) { su += __shfl_down(su, off); sd += __shfl_down(sd, off); }
    const int wv = tid >> 6;
    if ((tid & 63) == 0) { red[wv] = su; red[4 + wv] = sd; }
    __syncthreads();
    if (tid == 0) {
      const int par = t & 1;
      atomicAdd(&gacc[par * 16 + b],     red[0] + red[1] + red[2] + red[3]);
      atomicAdd(&gacc[par * 16 + 8 + b], red[4] + red[5] + red[6] + red[7]);
    }
  } else {
    if (t < 1) return;
    const int tau = t - 1;
    float* Wc    = sm;          // [96][32]
    float* W1L   = sm + 3072;   // [64][32]
    float* W2L   = sm + 5120;   // [64][8]
    float* boutL = sm + 5632;   // [32]
    float* b1L   = sm + 5664;   // [64]
    float* b2L   = sm + 5728;   // [8]
    for (int i = tid; i < 96 * 32; i += 256) { int j = i >> 5, g = i & 31; int k = j >> 5, hh = j & 31;
      Wc[j * 32 + g] = Wout[(g * 3 + k) * 32 + hh]; }
    for (int i = tid; i < 64 * 32; i += 256) { int r1 = i >> 5, g = i & 31; W1L[r1 * 32 + g] = W1[r1 * 32 + g]; }
    for (int i = tid; i < 512; i += 256) { int r1 = i >> 3, r = i & 7; W2L[r1 * 8 + r] = W2[r * 64 + r1]; }
    if (tid < 32) boutL[tid] = bout[tid];
    if (tid < 64) b1L[tid] = b1[tid];
    if (tid < 8)  b2L[tid] = b2[tid];
    __syncthreads();

    const int bo2 = bid - 512;
    const int b = bo2 >> 4, chunk = bo2 & 15;
    const int n = chunk * 256 + tid;
    const size_t zbase = (size_t)b * 32;

    f32x4 acc[8];
#pragma unroll
    for (int q = 0; q < 8; ++q) acc[q] = (f32x4)0.f;
    for (int j = 0; j < 96; ++j) {
      int k = j >> 5, hh = j & 31;
      float v = (k == 0) ? b2f(zt[(zbase + hh) * 4096 + n])
                         : b2f(zsh[(zbase + hh) * 8192 + (size_t)(k - 1) * 4096 + n]);
#pragma unroll
      for (int q = 0; q < 8; ++q) acc[q] += (*(const f32x4*)&Wc[j * 32 + q * 4]) * v;
    }
    f32x4 y[8];
#pragma unroll
    for (int q = 0; q < 8; ++q)
#pragma unroll
      for (int c = 0; c < 4; ++c) y[q][c] = tanh_f(acc[q][c] + boutL[q * 4 + c]);

    f32x4 o0 = { b2L[0], b2L[1], b2L[2], b2L[3] };
    f32x4 o1 = { b2L[4], b2L[5], b2L[6], b2L[7] };
    for (int r1 = 0; r1 < 64; ++r1) {
      f32x4 p = y[0] * (*(const f32x4*)&W1L[r1 * 32]);
#pragma unroll
      for (int q = 1; q < 8; ++q) p += y[q] * (*(const f32x4*)&W1L[r1 * 32 + q * 4]);
      float hv = b1L[r1] + p[0] + p[1] + p[2] + p[3];
      hv = fmaxf(hv, 0.f);
      o0 += (*(const f32x4*)&W2L[r1 * 8]) * hv;
      o1 += (*(const f32x4*)&W2L[r1 * 8 + 4]) * hv;
    }
    const size_t obase = ((size_t)b * 64 + tau) * 8 * 4096 + n;
#pragma unroll
    for (int r = 0; r < 4; ++r) {
      out[obase + (size_t)r * 4096]       = o0[r];
      out[obase + (size_t)(4 + r) * 4096] = o1[r];
    }
  }
}

// ---------- per-step state update (bf16 z out) + zero next parity gacc ----------
__global__ __launch_bounds__(256) void update_kernel(
    const float* __restrict__ zab, float* __restrict__ gacc,
    const float* __restrict__ bz, short* __restrict__ zout, int t) {
  const int par = t & 1;
  if (blockIdx.x == 0 && threadIdx.x < 16) gacc[(par ^ 1) * 16 + threadIdx.x] = 0.f;
  size_t idx = (size_t)blockIdx.x * 256 + threadIdx.x;   // 131072 threads
  size_t base = idx * 8;
  int row = (int)(base >> 12);
  int b = row >> 5, h = row & 31;
  float u  = gacc[par * 16 + b]     * (1.f / 131072.f);
  float fg = gacc[par * 16 + 8 + b] * (1.f / 131072.f);
  float bzv = bz[h];
  f32x4 za0 = *(const f32x4*)(zab + base),           za1 = *(const f32x4*)(zab + base + 4);
  f32x4 zb0 = *(const f32x4*)(zab + 1048576 + base), zb1 = *(const f32x4*)(zab + 1048576 + base + 4);
  bf16x8 ov;
#pragma unroll
  for (int i = 0; i < 4; ++i) {
    ov[i]     = f2b(tanh_f(u * za0[i] + fg * zb0[i] + bzv));
    ov[4 + i] = f2b(tanh_f(u * za1[i] + fg * zb1[i] + bzv));
  }
  *(bf16x8*)(zout + base) = ov;
}

// ---------- host ----------
extern "C" void kernel_launch(void* const* d_in, const int* in_sizes, int n_in,
                              void* d_out, int out_size, void* d_ws, size_t ws_size,
                              hipStream_t stream) {
  const float* x    = (const float*)d_in[0];
  const float* z0   = (const float*)d_in[1];
  const float* S    = (const float*)d_in[2];
  const float* Af   = (const float*)d_in[3];
  const float* Bw   = (const float*)d_in[4];
  const float* bz   = (const float*)d_in[5];
  const float* Ca   = (const float*)d_in[6];
  const float* Cb   = (const float*)d_in[7];
  const float* bc   = (const float*)d_in[8];
  const float* Da   = (const float*)d_in[9];
  const float* Db   = (const float*)d_in[10];
  const float* bd   = (const float*)d_in[11];
  const float* Wout = (const float*)d_in[12];
  const float* bo   = (const float*)d_in[13];
  const float* W1   = (const float*)d_in[14];
  const float* b1   = (const float*)d_in[15];
  const float* W2   = (const float*)d_in[16];
  const float* b2   = (const float*)d_in[17];
  float* out = (float*)d_out;

  // workspace layout (~151 MiB)
  char* w = (char*)d_ws;
  short* Scat = (short*)w; w += (size_t)8192 * 4096 * 2;   // bf16 [S ; S^2]          67.1 MB
  short* xsh  = (short*)w; w += (size_t)4096 * 8192 * 2;   // bf16 x shifts (tmp S^T) 67.1 MB
  short* zbuf = (short*)w; w += (size_t)2 * 1048576 * 2;   // bf16 z ping-pong         4.2 MB
  short* zsh  = (short*)w; w += (size_t)2097152 * 2;       // bf16 z shifts 256x8192   4.2 MB
  float* zab  = (float*)w; w += (size_t)2 * 1048576 * 4;   // fp32 za,zb               8.4 MB
  float* gacc = (float*)w; w += 256;                       // 2 parities x 16 floats
  size_t need = (size_t)(w - (char*)d_ws);
  if (ws_size < need) {
    fprintf(stderr, "kernel_launch: WS TOO SMALL need=%zu have=%zu -- NOT LAUNCHING\n",
            need, ws_size);
    return;
  }

  short* STt = xsh;  // temp: bf16 S^T (consumed by S^2 GEMM before xsh is written)

  conv_k<<<512, 256, 0, stream>>>(z0, zbuf, 131072);            // bf16 z_0
  conv_k<<<8192, 256, 0, stream>>>(S, Scat, 2097152);           // bf16 S
  transpose_k<<<dim3(128, 128), dim3(32, 8), 0, stream>>>(S, STt);
  gemm_pre<0><<<dim3(32, 32), 256, 0, stream>>>(Scat, STt, Scat + (size_t)4096 * 4096, 4096, 4096);
  gemm_pre<1><<<dim3(64, 32), 256, 0, stream>>>(x, Scat, xsh, 4096, 8192);
  hipMemsetAsync(gacc, 0, 128, stream);

  for (int t = 0; t <= 64; ++t) {
    short* zcur = zbuf + (size_t)(t & 1) * 1048576;
    short* znxt = zbuf + (size_t)((t + 1) & 1) * 1048576;
    gemm_zsh2<<<dim3(128, 2), 256, 0, stream>>>(zcur, Scat, zsh);
    gateout_kernel<<<640, 256, 0, stream>>>(x, xsh, zcur, zsh,
                                            Ca, Cb, bc, Da, Db, bd, Af, Bw,
                                            Wout, bo, W1, b1, W2, b2,
                                            zab, gacc, out, t);
    if (t < 64)
      update_kernel<<<512, 256, 0, stream>>>(zab, gacc, bz, znxt, t);
  }
}